// Round 1
// baseline (360.574 us; speedup 1.0000x reference)
//
#include <hip/hip_runtime.h>
#include <hip/hip_bf16.h>

// Problem constants (fixed by the reference)
#define NE    8      // experts
#define NTOK  1024   // tokens
#define NH    1024   // hidden
#define NI    1024   // intermediate (per half)
#define N13   2048   // 2*NI
#define NPAIR 2048   // NTOK * top_k

// Tiling
#define TM 32        // token-pairs per block tile
#define TN 128       // output columns per block tile
#define KT 16        // K-chunk

// ---------------------------------------------------------------------------
// Routing: per token softmax over 8 logits -> top-2 -> renormalize.
// Renormalized top-k softmax == 2-way softmax over the top-2 logits.
// Builds expert-grouped pair lists: pair_tok[p], pair_w[p], counts[e].
// ---------------------------------------------------------------------------
__global__ __launch_bounds__(256) void route_kernel(
    const float* __restrict__ logits,
    int* __restrict__ counts, int* __restrict__ basep,
    int* __restrict__ pair_tok, float* __restrict__ pair_w)
{
    __shared__ int s_cnt[NE];
    __shared__ int s_base[NE];
    const int tid = threadIdx.x;
    if (tid < NE) s_cnt[tid] = 0;
    __syncthreads();

    int   eA[4][2];
    int   slotA[4][2];
    float wA[4][2];

    #pragma unroll
    for (int i = 0; i < 4; i++) {
        const int t = tid * 4 + i;           // 256*4 = 1024 tokens
        float l[NE];
        #pragma unroll
        for (int e = 0; e < NE; e++) l[e] = logits[t * NE + e];
        // top-1 (ties -> lowest index, matching lax.top_k)
        int i0 = 0;
        #pragma unroll
        for (int e = 1; e < NE; e++) if (l[e] > l[i0]) i0 = e;
        // top-2
        int i1 = -1;
        #pragma unroll
        for (int e = 0; e < NE; e++) {
            if (e == i0) continue;
            if (i1 < 0 || l[e] > l[i1]) i1 = e;
        }
        const float e10 = __expf(l[i1] - l[i0]);   // <= 1
        const float inv = 1.0f / (1.0f + e10);
        eA[i][0] = i0; eA[i][1] = i1;
        wA[i][0] = inv; wA[i][1] = e10 * inv;
        slotA[i][0] = atomicAdd(&s_cnt[i0], 1);
        slotA[i][1] = atomicAdd(&s_cnt[i1], 1);
    }
    __syncthreads();
    if (tid == 0) {
        int acc = 0;
        #pragma unroll
        for (int e = 0; e < NE; e++) { s_base[e] = acc; acc += s_cnt[e]; }
    }
    __syncthreads();
    if (tid < NE) { counts[tid] = s_cnt[tid]; basep[tid] = s_base[tid]; }
    #pragma unroll
    for (int i = 0; i < 4; i++) {
        const int t = tid * 4 + i;
        #pragma unroll
        for (int k = 0; k < 2; k++) {
            const int p = s_base[eA[i][k]] + slotA[i][k];
            pair_tok[p] = t;
            pair_w[p]   = wA[i][k];
        }
    }
}

// ---------------------------------------------------------------------------
// Map a flat tile id to (expert, m-tile, n-tile) over expert-grouped rows.
// ---------------------------------------------------------------------------
__device__ __forceinline__ bool find_tile(
    const int* __restrict__ counts, int tile, int ntiles_n,
    int& e_o, int& mt_o, int& nt_o, int& cnt_o, int& base_o)
{
    int base = 0;
    #pragma unroll
    for (int e = 0; e < NE; e++) {
        const int cnt   = counts[e];
        const int mt    = (cnt + TM - 1) / TM;
        const int tiles = mt * ntiles_n;
        if (tile < tiles) {
            e_o = e; mt_o = tile / ntiles_n; nt_o = tile - (tile / ntiles_n) * ntiles_n;
            cnt_o = cnt; base_o = base; return true;
        }
        tile -= tiles; base += cnt;
    }
    return false;
}

// ---------------------------------------------------------------------------
// GEMM1: act[p, j] = silu(x_t . W13[e,:,j]) * (x_t . W13[e,:,NI+j])
// Tile: TM=32 pairs x TN=128 act-cols, K chunked by 16, fp32.
// Per-thread 4x4 register tile for gate and up.
// ---------------------------------------------------------------------------
__global__ __launch_bounds__(256) void gemm1_kernel(
    const float* __restrict__ X, const float* __restrict__ W13,
    const int* __restrict__ counts, const int* __restrict__ pair_tok,
    float* __restrict__ act)
{
    int e, mt, nt, cnt, base;
    if (!find_tile(counts, blockIdx.x, NI / TN, e, mt, nt, cnt, base)) return;

    __shared__ float Xs[KT][TM + 4];   // stride 36 floats: 16B-aligned rows, <=2-way banks
    __shared__ float Wg[KT][TN];
    __shared__ float Wu[KT][TN];

    const int tid  = threadIdx.x;
    const int c8   = tid & 31;   // col group (4 cols)
    const int r8   = tid >> 5;   // row group (4 rows), 0..7
    const int skk  = tid & 15;   // X staging: k within chunk
    const int srow = tid >> 4;   // X staging: local row 0..15 (and +16)
    const int wcol = (tid & 31) << 2;  // W staging col (float4)
    const int wrow = tid >> 5;         // W staging rows wrow, wrow+8

    const int lr0 = mt * TM + srow;
    const int lr1 = lr0 + 16;
    const int t0 = pair_tok[base + min(lr0, cnt - 1)];
    const int t1 = pair_tok[base + min(lr1, cnt - 1)];
    const float* xrow0 = X + (size_t)t0 * NH;
    const float* xrow1 = X + (size_t)t1 * NH;
    const float* wbase = W13 + (size_t)e * NH * N13 + nt * TN;

    float accg[4][4] = {};
    float accu[4][4] = {};

    for (int k0 = 0; k0 < NH; k0 += KT) {
        // stage X (transposed): Xs[k][row]
        Xs[skk][srow]      = xrow0[k0 + skk];
        Xs[skk][srow + 16] = xrow1[k0 + skk];
        // stage W13 gate & up tiles (coalesced float4 rows)
        const float* wg0 = wbase + (size_t)(k0 + wrow) * N13 + wcol;
        const float* wg1 = wbase + (size_t)(k0 + wrow + 8) * N13 + wcol;
        *reinterpret_cast<float4*>(&Wg[wrow][wcol])     = *reinterpret_cast<const float4*>(wg0);
        *reinterpret_cast<float4*>(&Wg[wrow + 8][wcol]) = *reinterpret_cast<const float4*>(wg1);
        *reinterpret_cast<float4*>(&Wu[wrow][wcol])     = *reinterpret_cast<const float4*>(wg0 + NI);
        *reinterpret_cast<float4*>(&Wu[wrow + 8][wcol]) = *reinterpret_cast<const float4*>(wg1 + NI);
        __syncthreads();

        #pragma unroll
        for (int kk = 0; kk < KT; kk++) {
            const float4 xv = *reinterpret_cast<const float4*>(&Xs[kk][r8 << 2]);
            const float4 gv = *reinterpret_cast<const float4*>(&Wg[kk][c8 << 2]);
            const float4 uv = *reinterpret_cast<const float4*>(&Wu[kk][c8 << 2]);
            const float xa[4] = {xv.x, xv.y, xv.z, xv.w};
            const float ga[4] = {gv.x, gv.y, gv.z, gv.w};
            const float ua[4] = {uv.x, uv.y, uv.z, uv.w};
            #pragma unroll
            for (int i2 = 0; i2 < 4; i2++) {
                #pragma unroll
                for (int j2 = 0; j2 < 4; j2++) {
                    accg[i2][j2] = fmaf(xa[i2], ga[j2], accg[i2][j2]);
                    accu[i2][j2] = fmaf(xa[i2], ua[j2], accu[i2][j2]);
                }
            }
        }
        __syncthreads();
    }

    // epilogue: silu(gate) * up
    #pragma unroll
    for (int i2 = 0; i2 < 4; i2++) {
        const int lr = mt * TM + (r8 << 2) + i2;
        if (lr < cnt) {
            const int p = base + lr;
            float* op = act + (size_t)p * NI + nt * TN + (c8 << 2);
            float4 o;
            {   float g = accg[i2][0], u = accu[i2][0];
                o.x = (g / (1.0f + __expf(-g))) * u; }
            {   float g = accg[i2][1], u = accu[i2][1];
                o.y = (g / (1.0f + __expf(-g))) * u; }
            {   float g = accg[i2][2], u = accu[i2][2];
                o.z = (g / (1.0f + __expf(-g))) * u; }
            {   float g = accg[i2][3], u = accu[i2][3];
                o.w = (g / (1.0f + __expf(-g))) * u; }
            *reinterpret_cast<float4*>(op) = o;
        }
    }
}

// ---------------------------------------------------------------------------
// GEMM2: out[t, h] += w_p * (act_p . W2[e,:,h]), atomic scatter-combine.
// ---------------------------------------------------------------------------
__global__ __launch_bounds__(256) void gemm2_kernel(
    const float* __restrict__ act, const float* __restrict__ W2,
    const int* __restrict__ counts, const int* __restrict__ pair_tok,
    const float* __restrict__ pair_w, float* __restrict__ out)
{
    int e, mt, nt, cnt, base;
    if (!find_tile(counts, blockIdx.x, NH / TN, e, mt, nt, cnt, base)) return;

    __shared__ float As[KT][TM + 4];
    __shared__ float Ws[KT][TN];

    const int tid  = threadIdx.x;
    const int c8   = tid & 31;
    const int r8   = tid >> 5;
    const int skk  = tid & 15;
    const int srow = tid >> 4;
    const int wcol = (tid & 31) << 2;
    const int wrow = tid >> 5;

    const int lr0 = mt * TM + srow;
    const int lr1 = lr0 + 16;
    const float* arow0 = act + (size_t)(base + min(lr0, cnt - 1)) * NI;
    const float* arow1 = act + (size_t)(base + min(lr1, cnt - 1)) * NI;
    const float* w2base = W2 + (size_t)e * NI * NH + nt * TN;

    float acc[4][4] = {};

    for (int k0 = 0; k0 < NI; k0 += KT) {
        As[skk][srow]      = arow0[k0 + skk];
        As[skk][srow + 16] = arow1[k0 + skk];
        *reinterpret_cast<float4*>(&Ws[wrow][wcol]) =
            *reinterpret_cast<const float4*>(w2base + (size_t)(k0 + wrow) * NH + wcol);
        *reinterpret_cast<float4*>(&Ws[wrow + 8][wcol]) =
            *reinterpret_cast<const float4*>(w2base + (size_t)(k0 + wrow + 8) * NH + wcol);
        __syncthreads();

        #pragma unroll
        for (int kk = 0; kk < KT; kk++) {
            const float4 xv = *reinterpret_cast<const float4*>(&As[kk][r8 << 2]);
            const float4 wv = *reinterpret_cast<const float4*>(&Ws[kk][c8 << 2]);
            const float xa[4] = {xv.x, xv.y, xv.z, xv.w};
            const float wa[4] = {wv.x, wv.y, wv.z, wv.w};
            #pragma unroll
            for (int i2 = 0; i2 < 4; i2++) {
                #pragma unroll
                for (int j2 = 0; j2 < 4; j2++) {
                    acc[i2][j2] = fmaf(xa[i2], wa[j2], acc[i2][j2]);
                }
            }
        }
        __syncthreads();
    }

    #pragma unroll
    for (int i2 = 0; i2 < 4; i2++) {
        const int lr = mt * TM + (r8 << 2) + i2;
        if (lr < cnt) {
            const int p = base + lr;
            const int t = pair_tok[p];
            const float w = pair_w[p];
            float* op = out + (size_t)t * NH + nt * TN + (c8 << 2);
            atomicAdd(op + 0, w * acc[i2][0]);
            atomicAdd(op + 1, w * acc[i2][1]);
            atomicAdd(op + 2, w * acc[i2][2]);
            atomicAdd(op + 3, w * acc[i2][3]);
        }
    }
}

// ---------------------------------------------------------------------------
extern "C" void kernel_launch(void* const* d_in, const int* in_sizes, int n_in,
                              void* d_out, int out_size, void* d_ws, size_t ws_size,
                              hipStream_t stream)
{
    const float* X      = (const float*)d_in[0];   // [T, H]
    const float* logits = (const float*)d_in[1];   // [T, E]
    const float* W13    = (const float*)d_in[2];   // [E, H, 2I]
    const float* W2     = (const float*)d_in[3];   // [E, I, H]
    // d_in[4] = top_k (always 2 for this problem)
    float* out = (float*)d_out;                    // [T, H]

    // workspace layout
    int*   counts   = (int*)d_ws;                  // [NE]
    int*   basep    = counts + NE;                 // [NE]
    int*   pair_tok = basep + NE;                  // [NPAIR]
    float* pair_w   = (float*)(pair_tok + NPAIR);  // [NPAIR]
    float* act      = pair_w + NPAIR;              // [NPAIR, NI]  (16B-aligned offset)

    hipMemsetAsync(d_out, 0, (size_t)NTOK * NH * sizeof(float), stream);
    route_kernel<<<1, 256, 0, stream>>>(logits, counts, basep, pair_tok, pair_w);

    // Max M-tiles over all experts: 2048/32 + (NE-1) = 71
    const int maxM = NPAIR / TM + NE - 1;
    gemm1_kernel<<<maxM * (NI / TN), 256, 0, stream>>>(X, W13, counts, pair_tok, act);
    gemm2_kernel<<<maxM * (NH / TN), 256, 0, stream>>>(act, W2, counts, pair_tok, pair_w, out);
}

// Round 2
// 195.964 us; speedup vs baseline: 1.8400x; 1.8400x over previous
//
#include <hip/hip_runtime.h>
#include <hip/hip_bf16.h>
#include <stdint.h>

#define NE    8
#define NTOK  1024
#define NH    1024
#define NI    1024
#define NPAIR 2048

typedef __attribute__((ext_vector_type(8))) short short8;
typedef __attribute__((ext_vector_type(4))) float f32x4;
typedef unsigned short u16;
typedef unsigned int   u32;

// fp32 -> bf16 round-to-nearest-even
__device__ __forceinline__ u16 f2bf(float x) {
    union { float f; u32 u; } v; v.f = x;
    return (u16)((v.u + 0x7fffu + ((v.u >> 16) & 1u)) >> 16);
}

// async global->LDS, 16B per lane (wave-uniform LDS base + lane*16)
__device__ __forceinline__ void async_ld16(u16* lds, const u16* g) {
    __builtin_amdgcn_global_load_lds(
        (const __attribute__((address_space(1))) u32*)g,
        (__attribute__((address_space(3))) u32*)lds, 16, 0, 0);
}

// ---------------------------------------------------------------------------
// Routing: softmax-top2 == 2-way softmax over top-2 logits. Produces
// expert-grouped pair list + per-token (pair0, pair1, w0, w1).
// ---------------------------------------------------------------------------
__global__ __launch_bounds__(256) void route_kernel(
    const float* __restrict__ logits,
    int* __restrict__ counts, int* __restrict__ pair_tok,
    int2* __restrict__ t2p, float2* __restrict__ t2w)
{
    __shared__ int s_cnt[NE];
    __shared__ int s_base[NE];
    const int tid = threadIdx.x;
    if (tid < NE) s_cnt[tid] = 0;
    __syncthreads();

    int eA[4][2]; int slotA[4][2]; float wA[4][2];

    #pragma unroll
    for (int i = 0; i < 4; i++) {
        const int t = tid * 4 + i;
        float l[NE];
        #pragma unroll
        for (int e = 0; e < NE; e++) l[e] = logits[t * NE + e];
        int i0 = 0;
        #pragma unroll
        for (int e = 1; e < NE; e++) if (l[e] > l[i0]) i0 = e;
        int i1 = -1;
        #pragma unroll
        for (int e = 0; e < NE; e++) {
            if (e == i0) continue;
            if (i1 < 0 || l[e] > l[i1]) i1 = e;
        }
        const float e10 = __expf(l[i1] - l[i0]);
        const float inv = 1.0f / (1.0f + e10);
        eA[i][0] = i0; eA[i][1] = i1;
        wA[i][0] = inv; wA[i][1] = e10 * inv;
        slotA[i][0] = atomicAdd(&s_cnt[i0], 1);
        slotA[i][1] = atomicAdd(&s_cnt[i1], 1);
    }
    __syncthreads();
    if (tid == 0) {
        int acc = 0;
        #pragma unroll
        for (int e = 0; e < NE; e++) { s_base[e] = acc; acc += s_cnt[e]; }
    }
    __syncthreads();
    if (tid < NE) counts[tid] = s_cnt[tid];
    #pragma unroll
    for (int i = 0; i < 4; i++) {
        const int t = tid * 4 + i;
        const int p0 = s_base[eA[i][0]] + slotA[i][0];
        const int p1 = s_base[eA[i][1]] + slotA[i][1];
        pair_tok[p0] = t;
        pair_tok[p1] = t;
        t2p[t] = make_int2(p0, p1);
        t2w[t] = make_float2(wA[i][0], wA[i][1]);
    }
}

// ---------------------------------------------------------------------------
__device__ __forceinline__ bool find_tile(
    const int* __restrict__ counts, int tile, int bm, int ntn,
    int& e_o, int& mt_o, int& nt_o, int& cnt_o, int& base_o)
{
    int base = 0;
    #pragma unroll
    for (int e = 0; e < NE; e++) {
        const int cnt = counts[e];
        const int mtiles = (cnt + bm - 1) / bm;
        const int tiles = mtiles * ntn;
        if (tile < tiles) {
            e_o = e; mt_o = tile / ntn; nt_o = tile - (tile / ntn) * ntn;
            cnt_o = cnt; base_o = base; return true;
        }
        tile -= tiles; base += cnt;
    }
    return false;
}

// ---------------------------------------------------------------------------
// X: fp32 -> bf16, straight copy (8 elems/thread)
// ---------------------------------------------------------------------------
__global__ __launch_bounds__(256) void cvt_x_kernel(
    const float* __restrict__ src, u16* __restrict__ dst)
{
    const int i = blockIdx.x * 256 + threadIdx.x;
    const float4* s = (const float4*)src;
    const float4 a = s[2 * i], b = s[2 * i + 1];
    uint4 o;
    o.x = f2bf(a.x) | ((u32)f2bf(a.y) << 16);
    o.y = f2bf(a.z) | ((u32)f2bf(a.w) << 16);
    o.z = f2bf(b.x) | ((u32)f2bf(b.y) << 16);
    o.w = f2bf(b.z) | ((u32)f2bf(b.w) << 16);
    *(uint4*)(dst + (size_t)i * 8) = o;
}

// ---------------------------------------------------------------------------
// Batched transpose+convert: src [E][K][N] fp32 -> dst [E][N][K] bf16.
// 64x64 tiles via fp32 LDS tile, stride 65 words (odd) -> <=2-way banks.
// ---------------------------------------------------------------------------
__global__ __launch_bounds__(256) void cvt_tr_kernel(
    const float* __restrict__ src, u16* __restrict__ dst, int K, int N)
{
    __shared__ float Ts[64][65];
    const int ktiles = K >> 6, ntiles = N >> 6;
    const int tpe = ktiles * ntiles;
    const int e = blockIdx.x / tpe;
    const int rem = blockIdx.x - e * tpe;
    const int kt = rem / ntiles, nt = rem - (rem / ntiles) * ntiles;
    const float* sb = src + ((size_t)e * K + (size_t)kt * 64) * N + nt * 64;
    const int tid = threadIdx.x;

    #pragma unroll
    for (int i = 0; i < 4; i++) {
        const int idx = tid + i * 256;
        const int r = idx >> 4, c = (idx & 15) << 2;
        const float4 v = *(const float4*)(sb + (size_t)r * N + c);
        Ts[r][c + 0] = v.x; Ts[r][c + 1] = v.y;
        Ts[r][c + 2] = v.z; Ts[r][c + 3] = v.w;
    }
    __syncthreads();
    u16* db = dst + ((size_t)e * N + (size_t)nt * 64) * K + kt * 64;
    #pragma unroll
    for (int i = 0; i < 2; i++) {
        const int u = tid + i * 256;          // 0..511
        const int n = u >> 3, k8 = (u & 7) << 3;
        uint4 o;
        o.x = f2bf(Ts[k8 + 0][n]) | ((u32)f2bf(Ts[k8 + 1][n]) << 16);
        o.y = f2bf(Ts[k8 + 2][n]) | ((u32)f2bf(Ts[k8 + 3][n]) << 16);
        o.z = f2bf(Ts[k8 + 4][n]) | ((u32)f2bf(Ts[k8 + 5][n]) << 16);
        o.w = f2bf(Ts[k8 + 6][n]) | ((u32)f2bf(Ts[k8 + 7][n]) << 16);
        *(uint4*)(db + (size_t)n * K + k8) = o;
    }
}

// ---------------------------------------------------------------------------
// GEMM1 (bf16 MFMA): act[p][c] = silu(x.Wg[c]) * (x.Wu[c])
// BM=128 pairs, 64 act cols (=128 weight cols), BK=32. 4 waves in 2x2.
// ---------------------------------------------------------------------------
__global__ __launch_bounds__(256) void gemm1_kernel(
    const u16* __restrict__ Xb, const u16* __restrict__ W13t,
    const int* __restrict__ counts, const int* __restrict__ pair_tok,
    u16* __restrict__ act)
{
    int e, mt, nt, cnt, base;
    if (!find_tile(counts, blockIdx.x, 128, NI / 64, e, mt, nt, cnt, base)) return;

    __shared__ u16 As[128 * 32];   // [pair-local][k], stride 32
    __shared__ u16 Bs[128 * 32];   // rows 0..63 gate cols, 64..127 up cols; [n][k]

    const int tid = threadIdx.x;
    const int ct = nt * 64;

    // staging: A 512 x 16B units (2/thread), B 512 units (2/thread)
    const int ra = tid >> 2, sa = (tid & 3) << 3;      // row 0..63, k-seg
    const int t0 = pair_tok[base + min(mt * 128 + ra, cnt - 1)];
    const int t1 = pair_tok[base + min(mt * 128 + 64 + ra, cnt - 1)];
    const u16* ga0 = Xb + (size_t)t0 * NH + sa;
    const u16* ga1 = Xb + (size_t)t1 * NH + sa;
    u16* la0 = As + tid * 8;
    u16* la1 = As + (tid + 256) * 8;

    const u16* gb0 = W13t + ((size_t)e * 2048 + ct + ra) * 1024 + sa;          // gate
    const u16* gb1 = W13t + ((size_t)e * 2048 + 1024 + ct + ra) * 1024 + sa;   // up
    u16* lb0 = Bs + tid * 8;
    u16* lb1 = Bs + (tid + 256) * 8;

    const int lane = tid & 63, w = tid >> 6;
    const int quad = lane >> 4, lid = lane & 15;
    const int rw = w >> 1, cw = w & 1;

    const short8* afp[4];
    const short8* bgp[2];
    const short8* bup[2];
    #pragma unroll
    for (int mi = 0; mi < 4; mi++)
        afp[mi] = (const short8*)(As + (rw * 64 + mi * 16 + lid) * 32 + quad * 8);
    #pragma unroll
    for (int nj = 0; nj < 2; nj++) {
        bgp[nj] = (const short8*)(Bs + (cw * 32 + nj * 16 + lid) * 32 + quad * 8);
        bup[nj] = (const short8*)(Bs + (64 + cw * 32 + nj * 16 + lid) * 32 + quad * 8);
    }

    f32x4 accg[4][2] = {};
    f32x4 accu[4][2] = {};

    for (int k0 = 0; k0 < NH; k0 += 32) {
        async_ld16(la0, ga0 + k0);
        async_ld16(la1, ga1 + k0);
        async_ld16(lb0, gb0 + k0);
        async_ld16(lb1, gb1 + k0);
        __syncthreads();
        short8 a[4], bg[2], bu[2];
        #pragma unroll
        for (int mi = 0; mi < 4; mi++) a[mi] = *afp[mi];
        #pragma unroll
        for (int nj = 0; nj < 2; nj++) { bg[nj] = *bgp[nj]; bu[nj] = *bup[nj]; }
        #pragma unroll
        for (int mi = 0; mi < 4; mi++) {
            #pragma unroll
            for (int nj = 0; nj < 2; nj++) {
                accg[mi][nj] = __builtin_amdgcn_mfma_f32_16x16x32_bf16(a[mi], bg[nj], accg[mi][nj], 0, 0, 0);
                accu[mi][nj] = __builtin_amdgcn_mfma_f32_16x16x32_bf16(a[mi], bu[nj], accu[mi][nj], 0, 0, 0);
            }
        }
        __syncthreads();
    }

    #pragma unroll
    for (int mi = 0; mi < 4; mi++) {
        #pragma unroll
        for (int nj = 0; nj < 2; nj++) {
            const int col = ct + cw * 32 + nj * 16 + lid;
            #pragma unroll
            for (int r = 0; r < 4; r++) {
                const int row = mt * 128 + rw * 64 + mi * 16 + quad * 4 + r;
                if (row < cnt) {
                    const float g = accg[mi][nj][r], u = accu[mi][nj][r];
                    const float s = g / (1.0f + __expf(-g)) * u;
                    act[(size_t)(base + row) * NI + col] = f2bf(s);
                }
            }
        }
    }
}

// ---------------------------------------------------------------------------
// GEMM2 (bf16 MFMA): down[p][h] = act[p] . W2t[e][h]
// BM=64 pairs, BN=128 h cols, BK=32. 4 waves side by side (1x4).
// ---------------------------------------------------------------------------
__global__ __launch_bounds__(256) void gemm2_kernel(
    const u16* __restrict__ act, const u16* __restrict__ W2t,
    const int* __restrict__ counts, float* __restrict__ down)
{
    int e, mt, nt, cnt, base;
    if (!find_tile(counts, blockIdx.x, 64, NH / 128, e, mt, nt, cnt, base)) return;

    __shared__ u16 As[64 * 32];    // [pair-local][k]
    __shared__ u16 Bs[128 * 32];   // [h-local][k]

    const int tid = threadIdx.x;
    const int ct = nt * 128;

    const int ra = tid >> 2, sa = (tid & 3) << 3;
    const int prow = base + min(mt * 64 + ra, cnt - 1);
    const u16* ga = act + (size_t)prow * NI + sa;
    u16* la = As + tid * 8;

    const u16* gb0 = W2t + ((size_t)e * 1024 + ct + ra) * NI + sa;
    const u16* gb1 = W2t + ((size_t)e * 1024 + ct + 64 + ra) * NI + sa;
    u16* lb0 = Bs + tid * 8;
    u16* lb1 = Bs + (tid + 256) * 8;

    const int lane = tid & 63, w = tid >> 6;
    const int quad = lane >> 4, lid = lane & 15;

    const short8* afp[4];
    const short8* bfp[2];
    #pragma unroll
    for (int mi = 0; mi < 4; mi++)
        afp[mi] = (const short8*)(As + (mi * 16 + lid) * 32 + quad * 8);
    #pragma unroll
    for (int nj = 0; nj < 2; nj++)
        bfp[nj] = (const short8*)(Bs + (w * 32 + nj * 16 + lid) * 32 + quad * 8);

    f32x4 acc[4][2] = {};

    for (int k0 = 0; k0 < NI; k0 += 32) {
        async_ld16(la, ga + k0);
        async_ld16(lb0, gb0 + k0);
        async_ld16(lb1, gb1 + k0);
        __syncthreads();
        short8 a[4], b[2];
        #pragma unroll
        for (int mi = 0; mi < 4; mi++) a[mi] = *afp[mi];
        #pragma unroll
        for (int nj = 0; nj < 2; nj++) b[nj] = *bfp[nj];
        #pragma unroll
        for (int mi = 0; mi < 4; mi++) {
            #pragma unroll
            for (int nj = 0; nj < 2; nj++)
                acc[mi][nj] = __builtin_amdgcn_mfma_f32_16x16x32_bf16(a[mi], b[nj], acc[mi][nj], 0, 0, 0);
        }
        __syncthreads();
    }

    #pragma unroll
    for (int mi = 0; mi < 4; mi++) {
        #pragma unroll
        for (int nj = 0; nj < 2; nj++) {
            const int col = ct + w * 32 + nj * 16 + lid;
            #pragma unroll
            for (int r = 0; r < 4; r++) {
                const int row = mt * 64 + mi * 16 + quad * 4 + r;
                if (row < cnt)
                    down[(size_t)(base + row) * NH + col] = acc[mi][nj][r];
            }
        }
    }
}

// ---------------------------------------------------------------------------
// Combine: out[t] = w0*down[p0] + w1*down[p1]   (replaces atomics + memset)
// ---------------------------------------------------------------------------
__global__ __launch_bounds__(256) void combine_kernel(
    const float* __restrict__ down, const int2* __restrict__ t2p,
    const float2* __restrict__ t2w, float* __restrict__ out)
{
    const int i = blockIdx.x * 256 + threadIdx.x;
    const int t = i >> 8;
    const int c = (i & 255) << 2;
    const int2 p = t2p[t];
    const float2 wv = t2w[t];
    const float4 d0 = *(const float4*)(down + (size_t)p.x * NH + c);
    const float4 d1 = *(const float4*)(down + (size_t)p.y * NH + c);
    float4 o;
    o.x = wv.x * d0.x + wv.y * d1.x;
    o.y = wv.x * d0.y + wv.y * d1.y;
    o.z = wv.x * d0.z + wv.y * d1.z;
    o.w = wv.x * d0.w + wv.y * d1.w;
    *(float4*)(out + (size_t)t * NH + c) = o;
}

// ---------------------------------------------------------------------------
extern "C" void kernel_launch(void* const* d_in, const int* in_sizes, int n_in,
                              void* d_out, int out_size, void* d_ws, size_t ws_size,
                              hipStream_t stream)
{
    const float* X      = (const float*)d_in[0];
    const float* logits = (const float*)d_in[1];
    const float* W13    = (const float*)d_in[2];
    const float* W2     = (const float*)d_in[3];
    float* out = (float*)d_out;

    char* ws = (char*)d_ws;
    int*    counts   = (int*)(ws + 0);
    int*    pair_tok = (int*)(ws + 256);
    int2*   t2p      = (int2*)(ws + 256 + 8192);
    float2* t2w      = (float2*)(ws + 256 + 16384);
    u16*    Xb       = (u16*)(ws + 65536);                 // 2 MiB
    u16*    W13t     = (u16*)(ws + 4194304);               // 32 MiB  [E][2I][H]
    u16*    W2t      = (u16*)(ws + 4194304 + 33554432);    // 16 MiB  [E][H][I]
    u16*    act      = (u16*)(ws + 54525952);              // 4 MiB   [P][I]
    float*  down     = (float*)(ws + 58720256);            // 8 MiB   [P][H]

    route_kernel<<<1, 256, 0, stream>>>(logits, counts, pair_tok, t2p, t2w);
    cvt_x_kernel<<<512, 256, 0, stream>>>(X, Xb);
    cvt_tr_kernel<<<NE * 16 * 32, 256, 0, stream>>>(W13, W13t, NH, 2 * NI);
    cvt_tr_kernel<<<NE * 16 * 16, 256, 0, stream>>>(W2, W2t, NI, NH);

    const int grid1 = (NPAIR / 128 + NE - 1) * (NI / 64);    // 368
    const int grid2 = (NPAIR / 64 + NE - 1) * (NH / 128);    // 312
    gemm1_kernel<<<grid1, 256, 0, stream>>>(Xb, W13t, counts, pair_tok, act);
    gemm2_kernel<<<grid2, 256, 0, stream>>>(act, W2t, counts, down);
    combine_kernel<<<NTOK * NH / 1024, 256, 0, stream>>>(down, t2p, t2w, out);
}